// Round 2
// baseline (195.696 us; speedup 1.0000x reference)
//
#include <hip/hip_runtime.h>
#include <hip/hip_bf16.h>
#include <cstdint>

#define OUT_LD 3584

typedef __bf16 bf16x8 __attribute__((ext_vector_type(8)));
typedef float  f32x4  __attribute__((ext_vector_type(4)));

__device__ __forceinline__ short f2bf(float v) {
  __hip_bfloat16 h = __float2bfloat16(v);
  return *reinterpret_cast<short*>(&h);
}

__device__ __forceinline__ void async16(const short* g, short* l) {
  __builtin_amdgcn_global_load_lds(
      (const __attribute__((address_space(1))) unsigned int*)g,
      (__attribute__((address_space(3))) unsigned int*)l, 16, 0, 0);
}

// C = A @ B^T epilogue-fused GEMM.
// A: [M,K] bf16 (lda=K), B: [N,K] bf16 (ldb=K).
// cols [0,nsplit):   eta path: eta_base[row*OUT_LD + col] = acc + bias[col]
// cols [nsplit,N):   relu path: rv=relu(acc); cbf[row*cld + cc]=bf16(rv);
//                    z_base[row*OUT_LD + cc] = rv   (cc = col-nsplit)
__global__ __launch_bounds__(256)
void gemm_bt_ep(const short* __restrict__ A, const short* __restrict__ B,
                int M, int N, int K, int nsplit,
                const float* __restrict__ bias,
                float* __restrict__ eta_base,
                float* __restrict__ z_base,
                short* __restrict__ cbf, int cld)
{
  __shared__ __align__(16) short sA[128*64];
  __shared__ __align__(16) short sB[128*64];

  const int tid  = threadIdx.x;
  const int lane = tid & 63;
  const int wid  = tid >> 6;
  const int bm   = blockIdx.x * 128;
  const int bn   = blockIdx.y * 128;
  const int wr   = (wid >> 1) * 64;   // wave row origin in tile
  const int wc   = (wid & 1) * 64;    // wave col origin in tile
  const int fr   = lane & 15;         // fragment row (A) / col (B)
  const int fk   = (lane >> 4) * 8;   // fragment k offset

  // staging: thread t loads 16B at (row = t/8, k = (t%8)*8) of the 128x64 tile,
  // 4 passes of 32 rows. LDS dest = wave-uniform base + lane*16 (linear layout).
  const int sr = tid >> 3;
  const int sc = (tid & 7) * 8;
  const short* ga0 = A + (size_t)(bm + sr) * K + sc;
  const short* gb0 = B + (size_t)(bn + sr) * K + sc;
  short* la = &sA[tid * 8];
  short* lb = &sB[tid * 8];

  f32x4 acc[4][4] = {};

  const int nk = K >> 6;

  #pragma unroll
  for (int p = 0; p < 4; ++p) {
    async16(ga0 + (size_t)(p*32) * K, la + p*2048);
    async16(gb0 + (size_t)(p*32) * K, lb + p*2048);
  }

  for (int kt = 0; kt < nk; ++kt) {
    __syncthreads();   // drains vmcnt -> staged tile visible
    #pragma unroll
    for (int kk = 0; kk < 2; ++kk) {
      bf16x8 a[4], b[4];
      #pragma unroll
      for (int i = 0; i < 4; ++i)
        a[i] = *(const bf16x8*)&sA[(wr + i*16 + fr)*64 + kk*32 + fk];
      #pragma unroll
      for (int j = 0; j < 4; ++j)
        b[j] = *(const bf16x8*)&sB[(wc + j*16 + fr)*64 + kk*32 + fk];
      #pragma unroll
      for (int i = 0; i < 4; ++i)
        #pragma unroll
        for (int j = 0; j < 4; ++j)
          acc[i][j] = __builtin_amdgcn_mfma_f32_16x16x32_bf16(a[i], b[j], acc[i][j], 0, 0, 0);
    }
    if (kt + 1 < nk) {
      __syncthreads();  // all waves done reading before overwrite
      const int koff = (kt + 1) * 64;
      #pragma unroll
      for (int p = 0; p < 4; ++p) {
        async16(ga0 + (size_t)(p*32) * K + koff, la + p*2048);
        async16(gb0 + (size_t)(p*32) * K + koff, lb + p*2048);
      }
    }
  }

  // epilogue: C/D layout col=lane&15, row=(lane>>4)*4+r
  const int r0 = (lane >> 4) * 4;
  #pragma unroll
  for (int i = 0; i < 4; ++i) {
    #pragma unroll
    for (int j = 0; j < 4; ++j) {
      const int col = bn + wc + j*16 + fr;
      #pragma unroll
      for (int r = 0; r < 4; ++r) {
        const int row = bm + wr + i*16 + r0 + r;
        float v = acc[i][j][r];
        if (col < nsplit) {
          eta_base[(size_t)row * OUT_LD + col] = v + bias[col];
        } else {
          float rv = v > 0.f ? v : 0.f;
          const int cc = col - nsplit;
          if (cbf) cbf[(size_t)row * cld + cc] = f2bf(rv);
          z_base[(size_t)row * OUT_LD + cc] = rv;
        }
      }
    }
  }
}

__global__ void cvt_bf16_4(const float* __restrict__ in, short* __restrict__ out, int n4) {
  int i = blockIdx.x * blockDim.x + threadIdx.x;
  const int stride = gridDim.x * blockDim.x;
  for (; i < n4; i += stride) {
    const float4 v = reinterpret_cast<const float4*>(in)[i];
    short4 o;
    o.x = f2bf(v.x); o.y = f2bf(v.y); o.z = f2bf(v.z); o.w = f2bf(v.w);
    reinterpret_cast<short4*>(out)[i] = o;
  }
}

// out[c*R + r] = bf16(in[r*C + c])   (in: [R][C] f32 -> out: [C][R] bf16)
__global__ void tcvt(const float* __restrict__ in, short* __restrict__ out, int R, int C) {
  const int idx = blockIdx.x * blockDim.x + threadIdx.x;
  if (idx >= R * C) return;
  const int c = idx / R;
  const int r = idx - c * R;
  out[idx] = f2bf(in[(size_t)r * C + c]);
}

extern "C" void kernel_launch(void* const* d_in, const int* in_sizes, int n_in,
                              void* d_out, int out_size, void* d_ws, size_t ws_size,
                              hipStream_t stream) {
  const float* Y  = (const float*)d_in[0];
  const float* W1 = (const float*)d_in[1];
  const float* W2 = (const float*)d_in[2];
  const float* W3 = (const float*)d_in[3];
  const float* b1 = (const float*)d_in[4];
  const float* b2 = (const float*)d_in[5];
  const float* b3 = (const float*)d_in[6];
  float* out = (float*)d_out;

  if (ws_size < 25165824) return;  // need ~24 MB scratch; fail visibly, don't corrupt

  char* ws = (char*)d_ws;
  short* Ybf  = (short*)(ws);                  // [4096][1024]
  short* c1bf = (short*)(ws + 8388608);        // [4096][512]
  short* c2bf = (short*)(ws + 12582912);       // [4096][512]
  short* c3bf = (short*)(ws + 16777216);       // [4096][512]
  short* B1   = (short*)(ws + 20971520);       // [512][1024]  = W1
  short* B2   = (short*)(ws + 22020096);       // [1536][512]  = [W1^T ; W2]
  short* B3   = (short*)(ws + 23592960);       // [1024][512]  = [W2^T ; W3]
  short* B4   = (short*)(ws + 24641536);       // [512][512]   = W3^T

  cvt_bf16_4<<<2048, 256, 0, stream>>>(Y,  Ybf,            4096*1024/4);
  cvt_bf16_4<<<512,  256, 0, stream>>>(W1, B1,             512*1024/4);
  cvt_bf16_4<<<256,  256, 0, stream>>>(W2, B2 + 1024*512,  512*512/4);
  cvt_bf16_4<<<256,  256, 0, stream>>>(W3, B3 + 512*512,   512*512/4);
  tcvt<<<(512*1024+255)/256, 256, 0, stream>>>(W1, B2, 512, 1024);
  tcvt<<<(512*512 +255)/256, 256, 0, stream>>>(W2, B3, 512, 512);
  tcvt<<<(512*512 +255)/256, 256, 0, stream>>>(W3, B4, 512, 512);

  // G1: c1 = relu(Y @ W1^T); also writes z1 (f32) to out[:,2048:2560)
  gemm_bt_ep<<<dim3(32, 4), 256, 0, stream>>>(Ybf, B1, 4096, 512, 1024,
      0, nullptr, nullptr, out + 2048, c1bf, 512);
  // G2: [eta1 | c2] = c1 @ [W1^T;W2]^T ; eta1 -> out[:,0:1024), z2 -> out[:,2560:3072)
  gemm_bt_ep<<<dim3(32, 12), 256, 0, stream>>>(c1bf, B2, 4096, 1536, 512,
      1024, b1, out, out + 2560, c2bf, 512);
  // G3: [eta2 | c3] ; eta2 -> out[:,1024:1536), z3 -> out[:,3072:3584)
  gemm_bt_ep<<<dim3(32, 8), 256, 0, stream>>>(c2bf, B3, 4096, 1024, 512,
      512, b2, out + 1024, out + 3072, c3bf, 512);
  // G4: eta3 -> out[:,1536:2048)
  gemm_bt_ep<<<dim3(32, 4), 256, 0, stream>>>(c3bf, B4, 4096, 512, 512,
      512, b3, out + 1536, nullptr, nullptr, 0);
}

// Round 3
// 138.808 us; speedup vs baseline: 1.4098x; 1.4098x over previous
//
#include <hip/hip_runtime.h>
#include <hip/hip_bf16.h>
#include <cstdint>

#define OUT_LD 3584

typedef __bf16 bf16x8 __attribute__((ext_vector_type(8)));
typedef float  f32x4  __attribute__((ext_vector_type(4)));

__device__ __forceinline__ short f2bf(float v) {
  __hip_bfloat16 h = __float2bfloat16(v);
  return *reinterpret_cast<short*>(&h);
}

__device__ __forceinline__ void async16(const short* g, short* l) {
  __builtin_amdgcn_global_load_lds(
      (const __attribute__((address_space(1))) unsigned int*)g,
      (__attribute__((address_space(3))) unsigned int*)l, 16, 0, 0);
}

// Core: C[bm:bm+BM, bn:bn+128] = A @ B^T slice, double-buffered 2-phase pipeline.
// A: [M,K] bf16, B: [N,K] bf16 (both row-major, ld=K).
// RELU=true : rv=relu(acc); cbf[row*cld+col]=bf16(rv); fout[row*OUT_LD+col]=rv
// RELU=false: fout[row*OUT_LD+col] = acc + bias[col]
template<int BM, int WAVES_M, int WAVES_N, bool RELU>
__device__ __forceinline__ void gemm_body(
    const short* __restrict__ A, const short* __restrict__ B, int K,
    int bm, int bn, const float* __restrict__ bias,
    float* __restrict__ fout, short* __restrict__ cbf, int cld)
{
  constexpr int WM = BM / WAVES_M;      // wave tile rows
  constexpr int WN = 128 / WAVES_N;     // wave tile cols
  constexpr int MR = WM / 16;
  constexpr int NR = WN / 16;
  constexpr int PA = BM / 32;           // A staging passes (32 rows per pass)

  __shared__ __align__(16) short sA[2][BM * 64];
  __shared__ __align__(16) short sB[2][128 * 64];

  const int tid  = threadIdx.x;
  const int lane = tid & 63;
  const int wid  = tid >> 6;
  const int wr = (wid / WAVES_N) * WM;
  const int wc = (wid % WAVES_N) * WN;
  const int fr = lane & 15;             // frag row (A) / col (B)
  const int fk = (lane >> 4) * 8;       // frag k offset

  // staging map: thread t -> (row = t/8, k = (t%8)*8), 32 rows per pass.
  const int sr = tid >> 3;
  const int sc = (tid & 7) * 8;
  const short* ga0 = A + (size_t)(bm + sr) * K + sc;
  const short* gb0 = B + (size_t)(bn + sr) * K + sc;

  f32x4 acc[MR][NR] = {};
  const int nk = K >> 6;

  auto stage = [&](int buf, int kt) {
    const int koff = kt * 64;
    #pragma unroll
    for (int p = 0; p < PA; ++p)
      async16(ga0 + (size_t)(p * 32) * K + koff, &sA[buf][tid * 8 + p * 2048]);
    #pragma unroll
    for (int p = 0; p < 4; ++p)
      async16(gb0 + (size_t)(p * 32) * K + koff, &sB[buf][tid * 8 + p * 2048]);
  };

  stage(0, 0);
  __syncthreads();                       // prologue drain (vmcnt(0) via syncthreads)
  int cur = 0;
  for (int kt = 0; kt < nk; ++kt) {
    if (kt + 1 < nk) stage(cur ^ 1, kt + 1);   // issue next tile BEFORE compute
    #pragma unroll
    for (int kk = 0; kk < 2; ++kk) {
      bf16x8 a[MR], b[NR];
      #pragma unroll
      for (int i = 0; i < MR; ++i)
        a[i] = *(const bf16x8*)&sA[cur][(wr + i * 16 + fr) * 64 + kk * 32 + fk];
      #pragma unroll
      for (int j = 0; j < NR; ++j)
        b[j] = *(const bf16x8*)&sB[cur][(wc + j * 16 + fr) * 64 + kk * 32 + fk];
      #pragma unroll
      for (int i = 0; i < MR; ++i)
        #pragma unroll
        for (int j = 0; j < NR; ++j)
          acc[i][j] = __builtin_amdgcn_mfma_f32_16x16x32_bf16(a[i], b[j], acc[i][j], 0, 0, 0);
    }
    __syncthreads();   // drains vmcnt(0): next buffer staged; all reads of cur done
    cur ^= 1;
  }

  // epilogue: C/D layout col=lane&15, row=(lane>>4)*4+r
  const int r0 = (lane >> 4) * 4;
  #pragma unroll
  for (int i = 0; i < MR; ++i) {
    #pragma unroll
    for (int j = 0; j < NR; ++j) {
      const int col = bn + wc + j * 16 + fr;
      #pragma unroll
      for (int r = 0; r < 4; ++r) {
        const int row = bm + wr + i * 16 + r0 + r;
        float v = acc[i][j][r];
        if (RELU) {
          float rv = v > 0.f ? v : 0.f;
          cbf[(size_t)row * cld + col] = f2bf(rv);
          fout[(size_t)row * OUT_LD + col] = rv;
        } else {
          fout[(size_t)row * OUT_LD + col] = v + bias[col];
        }
      }
    }
  }
}

// chain GEMMs: N=512, BM=64 -> grid (M/64, 4) = 256 blocks
template<int BM, int WAVES_M, int WAVES_N>
__global__ __launch_bounds__(256)
void gemm_relu(const short* __restrict__ A, const short* __restrict__ B, int K,
               float* __restrict__ zout, short* __restrict__ cbf) {
  gemm_body<BM, WAVES_M, WAVES_N, true>(A, B, K, blockIdx.x * BM, blockIdx.y * 128,
                                        nullptr, zout, cbf, 512);
}

// grouped eta GEMM: 512 blocks = eta1(256) + eta2(128) + eta3(128), BM=128
__global__ __launch_bounds__(256)
void gemm_eta(const short* __restrict__ c1, const short* __restrict__ c2,
              const short* __restrict__ c3, const short* __restrict__ W1T,
              const short* __restrict__ W2T, const short* __restrict__ W3T,
              const float* __restrict__ b1, const float* __restrict__ b2,
              const float* __restrict__ b3, float* __restrict__ out) {
  const int b = blockIdx.x;
  const short *A, *B; const float* bias; float* eo; int l;
  if (b < 256)      { l = b;       A = c1; B = W1T; bias = b1; eo = out; }
  else if (b < 384) { l = b - 256; A = c2; B = W2T; bias = b2; eo = out + 1024; }
  else              { l = b - 384; A = c3; B = W3T; bias = b3; eo = out + 1536; }
  const int bm = (l & 31) * 128;
  const int bn = (l >> 5) * 128;
  gemm_body<128, 2, 2, false>(A, B, 512, bm, bn, bias, eo, nullptr, 0);
}

// fused straight conversions: Y, W1, W2, W3 -> bf16 (float4 -> short4)
__global__ void prep_cvt(const float* __restrict__ Y, const float* __restrict__ W1,
                         const float* __restrict__ W2, const float* __restrict__ W3,
                         short* __restrict__ Ybf, short* __restrict__ W1b,
                         short* __restrict__ W2b, short* __restrict__ W3b) {
  const int i = blockIdx.x * 256 + threadIdx.x;   // grid sized exactly: 1310720 jobs
  const float* src; short* dst; int off;
  if (i < 1048576)      { src = Y;  dst = Ybf; off = i; }
  else if (i < 1179648) { src = W1; dst = W1b; off = i - 1048576; }
  else if (i < 1245184) { src = W2; dst = W2b; off = i - 1179648; }
  else                  { src = W3; dst = W3b; off = i - 1245184; }
  const float4 v = reinterpret_cast<const float4*>(src)[off];
  short4 o;
  o.x = f2bf(v.x); o.y = f2bf(v.y); o.z = f2bf(v.z); o.w = f2bf(v.w);
  reinterpret_cast<short4*>(dst)[off] = o;
}

// fused LDS-tiled transposes: W1T[1024][512], W2T[512][512], W3T[512][512] (bf16)
__global__ void prep_tr(const float* __restrict__ W1, const float* __restrict__ W2,
                        const float* __restrict__ W3, short* __restrict__ W1T,
                        short* __restrict__ W2T, short* __restrict__ W3T) {
  __shared__ short s[32][33];
  const int b = blockIdx.x;
  const float* in; short* out; int R, C, ti, tj;
  if (b < 512)      { in = W1; out = W1T; R = 512; C = 1024; ti = b >> 5; tj = b & 31; }
  else if (b < 768) { int l = b - 512; in = W2; out = W2T; R = 512; C = 512; ti = l >> 4; tj = l & 15; }
  else              { int l = b - 768; in = W3; out = W3T; R = 512; C = 512; ti = l >> 4; tj = l & 15; }
  const int r0 = ti * 32, c0 = tj * 32;
  const int tx = threadIdx.x & 31, ty = threadIdx.x >> 5;
  #pragma unroll
  for (int q = 0; q < 4; ++q)
    s[ty + q * 8][tx] = f2bf(in[(size_t)(r0 + ty + q * 8) * C + c0 + tx]);
  __syncthreads();
  #pragma unroll
  for (int q = 0; q < 4; ++q)
    out[(size_t)(c0 + ty + q * 8) * R + r0 + tx] = s[tx][ty + q * 8];
}

extern "C" void kernel_launch(void* const* d_in, const int* in_sizes, int n_in,
                              void* d_out, int out_size, void* d_ws, size_t ws_size,
                              hipStream_t stream) {
  const float* Y  = (const float*)d_in[0];
  const float* W1 = (const float*)d_in[1];
  const float* W2 = (const float*)d_in[2];
  const float* W3 = (const float*)d_in[3];
  const float* b1 = (const float*)d_in[4];
  const float* b2 = (const float*)d_in[5];
  const float* b3 = (const float*)d_in[6];
  float* out = (float*)d_out;

  if (ws_size < 25165824) return;  // need 24 MB scratch

  char* ws = (char*)d_ws;
  short* Ybf  = (short*)(ws);                  // [4096][1024]
  short* c1bf = (short*)(ws + 8388608);        // [4096][512]
  short* c2bf = (short*)(ws + 12582912);       // [4096][512]
  short* c3bf = (short*)(ws + 16777216);       // [4096][512]
  short* W1b  = (short*)(ws + 20971520);       // [512][1024]
  short* W2b  = (short*)(ws + 22020096);       // [512][512]
  short* W3b  = (short*)(ws + 22544384);       // [512][512]
  short* W1T  = (short*)(ws + 23068672);       // [1024][512]
  short* W2T  = (short*)(ws + 24117248);       // [512][512]
  short* W3T  = (short*)(ws + 24641536);       // [512][512]

  prep_cvt<<<5120, 256, 0, stream>>>(Y, W1, W2, W3, Ybf, W1b, W2b, W3b);
  prep_tr<<<1024, 256, 0, stream>>>(W1, W2, W3, W1T, W2T, W3T);

  // c1 = relu(Y @ W1^T); z1 -> out[:,2048:2560)
  gemm_relu<64, 1, 4><<<dim3(64, 4), 256, 0, stream>>>(Ybf, W1b, 1024, out + 2048, c1bf);
  // c2 = relu(c1 @ W2^T); z2 -> out[:,2560:3072)
  gemm_relu<64, 1, 4><<<dim3(64, 4), 256, 0, stream>>>(c1bf, W2b, 512, out + 2560, c2bf);
  // c3 = relu(c2 @ W3^T); z3 -> out[:,3072:3584)
  gemm_relu<64, 1, 4><<<dim3(64, 4), 256, 0, stream>>>(c2bf, W3b, 512, out + 3072, c3bf);
  // eta1|eta2|eta3 -> out[:,0:2048)
  gemm_eta<<<512, 256, 0, stream>>>(c1bf, c2bf, c3bf, W1T, W2T, W3T, b1, b2, b3, out);
}